// Round 2
// baseline (746.806 us; speedup 1.0000x reference)
//
#include <hip/hip_runtime.h>
#include <hip/hip_cooperative_groups.h>
#include <math.h>

namespace cg = cooperative_groups;

// Problem constants (fixed by the reference)
constexpr int Bn  = 32;
constexpr int Cn  = 256;
constexpr int Hn  = 64;
constexpr int Wn  = 64;
constexpr int HW  = Hn * Wn;        // 4096
constexpr int CHW = Cn * HW;        // 1048576
constexpr int HW4 = HW / 4;         // 1024 float4 per (b,c) plane
constexpr int NPOS  = Bn * HW;      // 131072 spatial positions
constexpr int NPOS4 = NPOS / 4;     // 32768 float4 positions

constexpr int GRID = 2048;          // 8 blocks/CU -> 32 waves/CU co-resident
constexpr int BLK  = 256;
constexpr int NTHREADS = GRID * BLK;          // 524288
constexpr int TOT4 = Bn * CHW / 4;            // 8388608 float4 elements of x/out

// -------------------------------------------------------------------------
// Fused cooperative kernel: reduce -> grid.sync -> conv+sigmoid -> grid.sync
// -> broadcast multiply. One dispatch; x stays L3-resident between phase 1
// and phase 3 (134 MB < 256 MB Infinity Cache; round-1 counters confirmed:
// FETCH = 133 MB = exactly one HBM read of x).
// __launch_bounds__(256, 8): 8 waves/SIMD -> VGPR capped at 64 so the full
// 2048-block cooperative grid is actually co-resident.
// -------------------------------------------------------------------------
__global__ __launch_bounds__(BLK, 8) void fused_k(const float* __restrict__ x,
                                                  const float* __restrict__ w,
                                                  float* __restrict__ out,
                                                  float* __restrict__ pmax,
                                                  float* __restrict__ pavg,
                                                  float* __restrict__ scale) {
    __shared__ float4 rmax[4][16];
    __shared__ float4 rsum[4][16];
    __shared__ float  sw[98];

    const int tid = threadIdx.x;
    if (tid < 98) sw[tid] = w[tid];      // barrier before use: phase-1 syncthreads

    // ---- Phase 1: channel-wise max + mean -------------------------------
    // Block owns 16 float4 spatial positions. Thread (posl, cg) reduces
    // channels [cg*16, cg*16+16) for position posl. Per load instruction a
    // wave covers 4 chunks of 16 consecutive float4 (256 B each) - coalesced.
    {
        const int posl = tid & 15;               // 0..15 position in tile
        const int cgp  = tid >> 4;               // 0..15 channel group
        const int wave = tid >> 6;               // 0..3
        const int lane = tid & 63;
        const int pos4 = blockIdx.x * 16 + posl; // 0..32767
        const int b    = pos4 >> 10;             // / HW4
        const int sp4  = pos4 & (HW4 - 1);

        const float4* xp = (const float4*)x + (size_t)b * (CHW / 4)
                           + (size_t)(cgp * 16) * HW4 + sp4;

        float4 mx = make_float4(-INFINITY, -INFINITY, -INFINITY, -INFINITY);
        float4 sm = make_float4(0.f, 0.f, 0.f, 0.f);

        #pragma unroll 4
        for (int c = 0; c < 16; ++c) {
            float4 v = xp[(size_t)c * HW4];
            mx.x = fmaxf(mx.x, v.x); mx.y = fmaxf(mx.y, v.y);
            mx.z = fmaxf(mx.z, v.z); mx.w = fmaxf(mx.w, v.w);
            sm.x += v.x; sm.y += v.y; sm.z += v.z; sm.w += v.w;
        }

        // In-wave combine across the 4 channel-groups held by this wave
        // (lanes differing in bits 4 and 5 share posl).
        #pragma unroll
        for (int mask = 16; mask <= 32; mask <<= 1) {
            mx.x = fmaxf(mx.x, __shfl_xor(mx.x, mask));
            mx.y = fmaxf(mx.y, __shfl_xor(mx.y, mask));
            mx.z = fmaxf(mx.z, __shfl_xor(mx.z, mask));
            mx.w = fmaxf(mx.w, __shfl_xor(mx.w, mask));
            sm.x += __shfl_xor(sm.x, mask);
            sm.y += __shfl_xor(sm.y, mask);
            sm.z += __shfl_xor(sm.z, mask);
            sm.w += __shfl_xor(sm.w, mask);
        }

        if (lane < 16) { rmax[wave][lane] = mx; rsum[wave][lane] = sm; }
        __syncthreads();

        if (tid < 16) {
            float4 M = rmax[0][tid];
            float4 S = rsum[0][tid];
            #pragma unroll
            for (int k = 1; k < 4; ++k) {
                float4 m2 = rmax[k][tid];
                float4 s2 = rsum[k][tid];
                M.x = fmaxf(M.x, m2.x); M.y = fmaxf(M.y, m2.y);
                M.z = fmaxf(M.z, m2.z); M.w = fmaxf(M.w, m2.w);
                S.x += s2.x; S.y += s2.y; S.z += s2.z; S.w += s2.w;
            }
            const float inv = 1.0f / (float)Cn;
            float4 A = make_float4(S.x * inv, S.y * inv, S.z * inv, S.w * inv);
            const int p = blockIdx.x * 16 + tid;
            ((float4*)pmax)[p] = M;
            ((float4*)pavg)[p] = A;
        }
    }

    cg::this_grid().sync();

    // ---- Phase 2: 7x7 conv (zero-pad 3) over [max, avg] + sigmoid -------
    // One thread per spatial position; only first NPOS threads work (blocks
    // are round-robined over CUs, so all CUs still participate).
    {
        const int idx = blockIdx.x * BLK + tid;  // 0..524287
        if (idx < NPOS) {
            const int b  = idx >> 12;            // / 4096
            const int sp = idx & 4095;
            const int h  = sp >> 6;
            const int wc = sp & 63;

            const float* pm = pmax + b * HW;
            const float* pa = pavg + b * HW;

            float acc = 0.f;
            #pragma unroll
            for (int kh = 0; kh < 7; ++kh) {
                const int hh = h + kh - 3;
                if (hh < 0 || hh >= Hn) continue;
                #pragma unroll
                for (int kw = 0; kw < 7; ++kw) {
                    const int ww = wc + kw - 3;
                    if (ww < 0 || ww >= Wn) continue;
                    const int o = hh * Wn + ww;
                    acc += pm[o] * sw[kh * 7 + kw] + pa[o] * sw[49 + kh * 7 + kw];
                }
            }
            scale[idx] = 1.f / (1.f + expf(-acc));
        }
    }

    cg::this_grid().sync();

    // ---- Phase 3: out = x * scale (broadcast over channels) -------------
    // Flat grid-stride over 8.4M float4; 16 iterations/thread; consecutive
    // threads -> consecutive float4 (perfect coalescing). x read hits L3;
    // scale (512 KB) hits L1/L2.
    {
        const float4* x4 = (const float4*)x;
        const float4* s4 = (const float4*)scale;
        float4* o4 = (float4*)out;

        size_t i4 = (size_t)blockIdx.x * BLK + tid;
        #pragma unroll 4
        for (int it = 0; it < TOT4 / NTHREADS; ++it, i4 += NTHREADS) {
            const int b   = (int)(i4 >> 18);         // / (CHW/4)
            const int hw4 = (int)(i4 & (HW4 - 1));
            const float4 s = s4[(b << 10) + hw4];
            const float4 v = x4[i4];
            float4 o;
            o.x = v.x * s.x; o.y = v.y * s.y;
            o.z = v.z * s.z; o.w = v.w * s.w;
            o4[i4] = o;
        }
    }
}

// -------------------------------------------------------------------------
// Fallback path (round-0 3-kernel version) in case the cooperative launch
// is rejected (e.g. co-residency validation fails).
// -------------------------------------------------------------------------
__global__ __launch_bounds__(256) void reduce_k(const float* __restrict__ x,
                                                float* __restrict__ pmax,
                                                float* __restrict__ pavg) {
    __shared__ float4 smax[4][64];
    __shared__ float4 ssum[4][64];

    const int lane  = threadIdx.x & 63;
    const int chunk = threadIdx.x >> 6;
    const int pos4  = blockIdx.x * 64 + lane;
    const int b     = pos4 >> 10;
    const int sp4   = pos4 & (HW4 - 1);

    const float4* xp = (const float4*)x + (size_t)b * (CHW / 4)
                       + (size_t)(chunk * 64) * HW4 + sp4;

    float4 mx = make_float4(-INFINITY, -INFINITY, -INFINITY, -INFINITY);
    float4 sm = make_float4(0.f, 0.f, 0.f, 0.f);

    #pragma unroll 8
    for (int c = 0; c < 64; ++c) {
        float4 v = xp[(size_t)c * HW4];
        mx.x = fmaxf(mx.x, v.x); mx.y = fmaxf(mx.y, v.y);
        mx.z = fmaxf(mx.z, v.z); mx.w = fmaxf(mx.w, v.w);
        sm.x += v.x; sm.y += v.y; sm.z += v.z; sm.w += v.w;
    }

    smax[chunk][lane] = mx;
    ssum[chunk][lane] = sm;
    __syncthreads();

    if (chunk == 0) {
        float4 M = smax[0][lane];
        float4 S = ssum[0][lane];
        #pragma unroll
        for (int k = 1; k < 4; ++k) {
            float4 m2 = smax[k][lane];
            float4 s2 = ssum[k][lane];
            M.x = fmaxf(M.x, m2.x); M.y = fmaxf(M.y, m2.y);
            M.z = fmaxf(M.z, m2.z); M.w = fmaxf(M.w, m2.w);
            S.x += s2.x; S.y += s2.y; S.z += s2.z; S.w += s2.w;
        }
        const float inv = 1.0f / (float)Cn;
        float4 A = make_float4(S.x * inv, S.y * inv, S.z * inv, S.w * inv);
        ((float4*)pmax)[pos4] = M;
        ((float4*)pavg)[pos4] = A;
    }
}

__global__ __launch_bounds__(256) void conv_k(const float* __restrict__ pmax,
                                              const float* __restrict__ pavg,
                                              const float* __restrict__ w,
                                              float* __restrict__ scale) {
    __shared__ float sw[98];
    if (threadIdx.x < 98) sw[threadIdx.x] = w[threadIdx.x];
    __syncthreads();

    const int idx = blockIdx.x * blockDim.x + threadIdx.x;
    const int b   = idx >> 12;
    const int sp  = idx & 4095;
    const int h   = sp >> 6;
    const int wc  = sp & 63;

    const float* pm = pmax + b * HW;
    const float* pa = pavg + b * HW;

    float acc = 0.f;
    #pragma unroll
    for (int kh = 0; kh < 7; ++kh) {
        const int hh = h + kh - 3;
        if (hh < 0 || hh >= Hn) continue;
        #pragma unroll
        for (int kw = 0; kw < 7; ++kw) {
            const int ww = wc + kw - 3;
            if (ww < 0 || ww >= Wn) continue;
            const int o = hh * Wn + ww;
            acc += pm[o] * sw[kh * 7 + kw] + pa[o] * sw[49 + kh * 7 + kw];
        }
    }
    scale[idx] = 1.f / (1.f + expf(-acc));
}

__global__ __launch_bounds__(256) void mul_k(const float* __restrict__ x,
                                             const float* __restrict__ scale,
                                             float* __restrict__ out) {
    const long long i4 = (long long)blockIdx.x * 256 + threadIdx.x;
    const int b   = (int)(i4 >> 18);
    const int hw4 = (int)(i4 & (HW4 - 1));

    const float4 s = ((const float4*)scale)[b * HW4 + hw4];
    const float4 v = ((const float4*)x)[i4];
    float4 o;
    o.x = v.x * s.x; o.y = v.y * s.y; o.z = v.z * s.z; o.w = v.w * s.w;
    ((float4*)out)[i4] = o;
}

extern "C" void kernel_launch(void* const* d_in, const int* in_sizes, int n_in,
                              void* d_out, int out_size, void* d_ws, size_t ws_size,
                              hipStream_t stream) {
    const float* x = (const float*)d_in[0];
    const float* w = (const float*)d_in[1];
    float* out = (float*)d_out;

    // Workspace layout (floats): pmax[NPOS] | pavg[NPOS] | scale[NPOS] = 1.5 MB
    float* pmax  = (float*)d_ws;
    float* pavg  = pmax + NPOS;
    float* scale = pavg + NPOS;

    void* args[] = { (void*)&x, (void*)&w, (void*)&out,
                     (void*)&pmax, (void*)&pavg, (void*)&scale };

    hipError_t err = hipLaunchCooperativeKernel((const void*)fused_k,
                                                dim3(GRID), dim3(BLK),
                                                args, 0, stream);
    if (err != hipSuccess) {
        // Fallback: original 3-kernel path.
        reduce_k<<<NPOS4 / 64, 256, 0, stream>>>(x, pmax, pavg);
        conv_k<<<NPOS / 256, 256, 0, stream>>>(pmax, pavg, w, scale);
        mul_k<<<(Bn * CHW / 4) / 256, 256, 0, stream>>>(x, scale, out);
    }
}

// Round 3
// 263.687 us; speedup vs baseline: 2.8322x; 2.8322x over previous
//
#include <hip/hip_runtime.h>
#include <math.h>

// Problem constants (fixed by the reference)
constexpr int Bn  = 32;
constexpr int Cn  = 256;
constexpr int Hn  = 64;
constexpr int Wn  = 64;
constexpr int HW  = Hn * Wn;        // 4096
constexpr int CHW = Cn * HW;        // 1048576
constexpr int HW4 = HW / 4;         // 1024 float4 per (b,c) plane
constexpr int NPOS  = Bn * HW;      // 131072 spatial positions
constexpr int NPOS4 = NPOS / 4;     // 32768 float4 positions

constexpr int MUL_GRID = 2048;      // 8 blocks/CU, persistent grid-stride
constexpr int MUL_BLK  = 256;
constexpr int MUL_NTH  = MUL_GRID * MUL_BLK;   // 524288
constexpr int TOT4     = Bn * CHW / 4;         // 8388608 float4 of x/out
constexpr int MUL_IT   = TOT4 / MUL_NTH;       // 16 iterations/thread

// -------------------------------------------------------------------------
// Kernel 1: channel-wise max + mean.
// 512 blocks x 512 threads (8 waves). Wave `chunk` reduces channels
// [chunk*32, chunk*32+32) for the block's 64 consecutive float4 positions.
// Each load instr: 64 lanes x 16 B contiguous = 1 KiB coalesced.
// 16 waves/CU (2 blocks/CU) -- 2x the TLP of the round-0 version.
// NOTE: cooperative grid.sync fusion was tried (rounds 1-2) and is
// structurally dead on MI355X: sync spin costs ~70-250us/barrier, scaling
// with block count (cross-XCD device-scope polling). Separate dispatches
// win; L3 keeps x (134 MB < 256 MB) resident between kernel 1 and 3.
// -------------------------------------------------------------------------
__global__ __launch_bounds__(512, 4) void reduce_k(const float* __restrict__ x,
                                                   float* __restrict__ pmax,
                                                   float* __restrict__ pavg) {
    __shared__ float4 smax[8][64];
    __shared__ float4 ssum[8][64];

    const int lane  = threadIdx.x & 63;
    const int chunk = threadIdx.x >> 6;           // 0..7 (wave id)
    const int pos4  = blockIdx.x * 64 + lane;     // 0..32767
    const int b     = pos4 >> 10;                 // / HW4 (block never straddles b)
    const int sp4   = pos4 & (HW4 - 1);

    const float4* xp = (const float4*)x + (size_t)b * (CHW / 4)
                       + (size_t)(chunk * 32) * HW4 + sp4;

    float4 mx = make_float4(-INFINITY, -INFINITY, -INFINITY, -INFINITY);
    float4 sm = make_float4(0.f, 0.f, 0.f, 0.f);

    #pragma unroll 8
    for (int c = 0; c < 32; ++c) {
        float4 v = xp[(size_t)c * HW4];
        mx.x = fmaxf(mx.x, v.x); mx.y = fmaxf(mx.y, v.y);
        mx.z = fmaxf(mx.z, v.z); mx.w = fmaxf(mx.w, v.w);
        sm.x += v.x; sm.y += v.y; sm.z += v.z; sm.w += v.w;
    }

    smax[chunk][lane] = mx;
    ssum[chunk][lane] = sm;
    __syncthreads();

    if (chunk == 0) {
        float4 M = smax[0][lane];
        float4 S = ssum[0][lane];
        #pragma unroll
        for (int k = 1; k < 8; ++k) {
            float4 m2 = smax[k][lane];
            float4 s2 = ssum[k][lane];
            M.x = fmaxf(M.x, m2.x); M.y = fmaxf(M.y, m2.y);
            M.z = fmaxf(M.z, m2.z); M.w = fmaxf(M.w, m2.w);
            S.x += s2.x; S.y += s2.y; S.z += s2.z; S.w += s2.w;
        }
        const float inv = 1.0f / (float)Cn;
        float4 A = make_float4(S.x * inv, S.y * inv, S.z * inv, S.w * inv);
        ((float4*)pmax)[pos4] = M;
        ((float4*)pavg)[pos4] = A;
    }
}

// -------------------------------------------------------------------------
// Kernel 2: 7x7 conv (cross-correlation, zero-pad 3) over [max, avg]
// + sigmoid. One thread per spatial position; weights staged in LDS.
// Pooled arrays (1 MB) are L2/L3-resident; ~4us.
// -------------------------------------------------------------------------
__global__ __launch_bounds__(256) void conv_k(const float* __restrict__ pmax,
                                              const float* __restrict__ pavg,
                                              const float* __restrict__ w,
                                              float* __restrict__ scale) {
    __shared__ float sw[98];
    if (threadIdx.x < 98) sw[threadIdx.x] = w[threadIdx.x];
    __syncthreads();

    const int idx = blockIdx.x * blockDim.x + threadIdx.x;   // 0..131071
    const int b   = idx >> 12;           // / 4096
    const int sp  = idx & 4095;
    const int h   = sp >> 6;
    const int wc  = sp & 63;

    const float* pm = pmax + b * HW;
    const float* pa = pavg + b * HW;

    float acc = 0.f;
    #pragma unroll
    for (int kh = 0; kh < 7; ++kh) {
        const int hh = h + kh - 3;
        if (hh < 0 || hh >= Hn) continue;
        #pragma unroll
        for (int kw = 0; kw < 7; ++kw) {
            const int ww = wc + kw - 3;
            if (ww < 0 || ww >= Wn) continue;
            const int o = hh * Wn + ww;
            acc += pm[o] * sw[kh * 7 + kw] + pa[o] * sw[49 + kh * 7 + kw];
        }
    }
    scale[idx] = 1.f / (1.f + expf(-acc));
}

// -------------------------------------------------------------------------
// Kernel 3: out = x * scale (broadcast over channels).
// Persistent grid-stride: 2048 blocks x 256 thr, 16 float4/thread.
// (Round-0 used 32768 one-shot blocks: 1 float4/thread meant block
// startup/teardown per two memory ops -- poor latency hiding.)
// Consecutive threads -> consecutive float4 (perfect coalescing); x re-read
// is L3-resident from kernel 1; scale (512 KB) hits L1/L2.
// -------------------------------------------------------------------------
__global__ __launch_bounds__(MUL_BLK, 8) void mul_k(const float* __restrict__ x,
                                                    const float* __restrict__ scale,
                                                    float* __restrict__ out) {
    const float4* x4 = (const float4*)x;
    const float4* s4 = (const float4*)scale;
    float4* o4 = (float4*)out;

    size_t i4 = (size_t)blockIdx.x * MUL_BLK + threadIdx.x;
    #pragma unroll 4
    for (int it = 0; it < MUL_IT; ++it, i4 += MUL_NTH) {
        const int b   = (int)(i4 >> 18);         // / (CHW/4)
        const int hw4 = (int)(i4 & (HW4 - 1));
        const float4 s = s4[(b << 10) + hw4];
        const float4 v = x4[i4];
        float4 o;
        o.x = v.x * s.x; o.y = v.y * s.y;
        o.z = v.z * s.z; o.w = v.w * s.w;
        o4[i4] = o;
    }
}

extern "C" void kernel_launch(void* const* d_in, const int* in_sizes, int n_in,
                              void* d_out, int out_size, void* d_ws, size_t ws_size,
                              hipStream_t stream) {
    const float* x = (const float*)d_in[0];
    const float* w = (const float*)d_in[1];
    float* out = (float*)d_out;

    // Workspace layout (floats): pmax[NPOS] | pavg[NPOS] | scale[NPOS] = 1.5 MB
    float* pmax  = (float*)d_ws;
    float* pavg  = pmax + NPOS;
    float* scale = pavg + NPOS;

    // Pass 1: channel max/mean. 512 blocks x 512 thr (8 waves, 32-ch chunks).
    reduce_k<<<NPOS4 / 64, 512, 0, stream>>>(x, pmax, pavg);

    // Pass 2: 7x7 conv + sigmoid. 512 blocks x 256 thr.
    conv_k<<<NPOS / 256, 256, 0, stream>>>(pmax, pavg, w, scale);

    // Pass 3: broadcast multiply. Persistent 2048-block grid-stride.
    mul_k<<<MUL_GRID, MUL_BLK, 0, stream>>>(x, scale, out);
}